// Round 10
// baseline (219.048 us; speedup 1.0000x reference)
//
#include <hip/hip_runtime.h>
#include <stdint.h>

#define NB 4
#define NWS 64
#define TT 65536
#define TCC 1024
#define CEE 128
#define WW 16

#define INV2PI 0.15915494309189535f

// ws layout (float offsets)
#define OFF_FILM  0                           // 1048576
#define OFF_SB    (OFF_FILM + NB*256*TCC)     // 4096: S[b][tc] = sum_n mw*bn
#define OFF_W0S   (OFF_SB + NB*TCC)           // 1024
#define OFF_B0S   (OFF_W0S + 1024)
#define OFF_B1S   (OFF_B0S + 1024)
#define OFF_B2S   (OFF_B1S + 1024)            // 64
#define OFF_AFRAG (OFF_B2S + 64)              // 4096 uint4 = 16384 floats
#define OFF_WF    (OFF_AFRAG + 16384)         // 12288 uint4 = 49152 floats (hidden W frags)
#define OFF_W3F   (OFF_WF + 49152)            // 8192 uint4 = 32768 floats (final W frags)
#define OFF_PART  (OFF_W3F + 32768)           // 4*NB*TT floats

typedef _Float16 half4_t __attribute__((ext_vector_type(4)));
typedef _Float16 half2_t __attribute__((ext_vector_type(2)));
typedef __fp16 fp16x2_t __attribute__((ext_vector_type(2)));
typedef float f32x4_t __attribute__((ext_vector_type(4)));
typedef float f32x2_t __attribute__((ext_vector_type(2)));

union H4 { half4_t h4; half2_t h2[2]; fp16x2_t f2[2]; uint2 u; };

__device__ __forceinline__ float sinrev(float r) {
  // sin(2*pi*r); args bounded well inside HW +-256 revolution range
  return __builtin_amdgcn_sinf(r);
}

// ---------------- prep: shaper weights + MLP weight fragments --------------
__global__ __launch_bounds__(256) void k_prep(
    const float* __restrict__ iscale,
    const float* __restrict__ sw0, const float* __restrict__ sb0,
    const float* __restrict__ sw1, const float* __restrict__ sb1,
    const float* __restrict__ sw2, const float* __restrict__ sb2,
    const float* __restrict__ m0, const float* __restrict__ m1,
    const float* __restrict__ m2, const float* __restrict__ m3,
    float* __restrict__ ws) {
  const int tid = threadIdx.x;
  const int bx = blockIdx.x;
  if (bx < 16) {
    int i = bx * 256 + tid;             // 0..4095
    if (i < NWS * WW) {
      int n = i / WW;
      ws[OFF_W0S + i] = sw0[i] * iscale[n] * INV2PI;
      ws[OFF_B0S + i] = sb0[i] * INV2PI;
      ws[OFF_B1S + i] = sb1[i] * INV2PI;
    }
    if (i < NWS) ws[OFF_B2S + i] = sb2[i] * INV2PI;
    {
      int n = i >> 6, l = i & 63;
      int m = l & 15, k0 = (l >> 4) * 4;
      H4 a1, a2;
      #pragma unroll
      for (int j = 0; j < 4; ++j) {
        a1.h4[j] = (_Float16)(sw1[(n * 16 + m) * 16 + k0 + j] * INV2PI);
        a2.h4[j] = (_Float16)(sw2[n * 16 + k0 + j] * INV2PI);
      }
      uint4 o; o.x = a1.u.x; o.y = a1.u.y; o.z = a2.u.x; o.w = a2.u.y;
      ((uint4*)(ws + OFF_AFRAG))[i] = o;
    }
  } else if (bx < 64) {
    // hidden-layer W fragments: B[k][n=ch]: lane holds W[ct*16+l16][kt*16+quad*4+j]
    int i = (bx - 16) * 256 + tid;      // 0..12287 = ((L*8+kt)*8+ct)*64+lane
    int l = i & 63, ct = (i >> 6) & 7, kt = (i >> 9) & 7, L = i >> 12;
    const float* W = (L == 0) ? m0 : (L == 1 ? m1 : m2);
    int o = ct * 16 + (l & 15);
    int k0 = kt * 16 + (l >> 4) * 4;
    H4 hi, lo;
    #pragma unroll
    for (int j = 0; j < 4; ++j) {
      float v = W[o * CEE + k0 + j];
      _Float16 h = (_Float16)v;
      hi.h4[j] = h;
      lo.h4[j] = (_Float16)(v - (float)h);
    }
    uint4 q; q.x = hi.u.x; q.y = hi.u.y; q.z = lo.u.x; q.w = lo.u.y;
    ((uint4*)(ws + OFF_WF))[i] = q;
  } else {
    // final-layer (CE->256) fragments: (kt*16 + ct)*64 + lane
    int i = (bx - 64) * 256 + tid;      // 0..8191
    int l = i & 63, ct = (i >> 6) & 15, kt = i >> 10;
    int o = ct * 16 + (l & 15);
    int k0 = kt * 16 + (l >> 4) * 4;
    H4 hi, lo;
    #pragma unroll
    for (int j = 0; j < 4; ++j) {
      float v = m3[o * CEE + k0 + j];
      _Float16 h = (_Float16)v;
      hi.h4[j] = h;
      lo.h4[j] = (_Float16)(v - (float)h);
    }
    uint4 q; q.x = hi.u.x; q.y = hi.u.y; q.z = lo.u.x; q.w = lo.u.y;
    ((uint4*)(ws + OFF_W3F))[i] = q;
  }
}

// pack x (16 pos x 128 ch fp32 in h) into MFMA A-fragments, f16 hi/lo split
__device__ __forceinline__ void pack_frags(
    const float* h, uint2* XH, uint2* XL,
    const float* MU, const float* RS,
    const float* __restrict__ g, const float* __restrict__ e,
    bool doLN, int tid) {
  #pragma unroll
  for (int i = 0; i < 2; ++i) {
    int w = tid + i * 256;
    int l = w & 63, kt = w >> 6;
    int m = l & 15, k0 = kt * 16 + (l >> 4) * 4;
    float x[4];
    #pragma unroll
    for (int j = 0; j < 4; ++j) {
      float v = h[m * 137 + k0 + j];
      if (doLN) {
        v = (v - MU[m]) * RS[m] * g[k0 + j] + e[k0 + j];
        v = fmaxf(v, 0.01f * v);
      }
      x[j] = v;
    }
    H4 hi;
    hi.f2[0] = __builtin_amdgcn_cvt_pkrtz(x[0], x[1]);
    hi.f2[1] = __builtin_amdgcn_cvt_pkrtz(x[2], x[3]);
    float l0 = x[0] - (float)hi.h4[0];
    float l1 = x[1] - (float)hi.h4[1];
    float l2 = x[2] - (float)hi.h4[2];
    float l3 = x[3] - (float)hi.h4[3];
    H4 lo;
    lo.f2[0] = __builtin_amdgcn_cvt_pkrtz(l0, l1);
    lo.f2[1] = __builtin_amdgcn_cvt_pkrtz(l2, l3);
    XH[kt * 64 + l] = hi.u;
    XL[kt * 64 + l] = lo.u;
  }
}

// ---------------- kernel 1: MFMA TimeDistributedMLP -> film + S ------------
// grid: 4 b x 64 tc-tiles = 256 blocks; block 256 threads (4 waves)
__global__ __launch_bounds__(256) void k_mlp(
    const float* __restrict__ ce,
    const float* __restrict__ b0, const float* __restrict__ g0, const float* __restrict__ e0,
    const float* __restrict__ b1, const float* __restrict__ g1, const float* __restrict__ e1,
    const float* __restrict__ b2, const float* __restrict__ g2, const float* __restrict__ e2,
    const float* __restrict__ b3,
    const float* __restrict__ mixw,
    float* __restrict__ ws) {
  const int tid = threadIdx.x;
  const int lane = tid & 63;
  const int wv = tid >> 6;
  const int l16 = lane & 15;
  const int quad = lane >> 4;
  const int bx = blockIdx.x;
  const int b = bx >> 6;
  const int tc0 = (bx & 63) * 16;

  __shared__ float h[16 * 137];        // [pos][ch] fp32
  __shared__ float h2[16 * 265];       // final [pos][ch256]
  __shared__ uint2 XH[8 * 64], XL[8 * 64];
  __shared__ float MU[16], RS[16];

  // stage ce tile -> h (transpose)
  {
    int ch = tid >> 1, hf = tid & 1;
    const float* src = ce + ((size_t)(b * CEE + ch)) * TCC + tc0 + hf * 8;
    float4 v0 = *(const float4*)src;
    float4 v1 = *(const float4*)(src + 4);
    float vv[8] = {v0.x, v0.y, v0.z, v0.w, v1.x, v1.y, v1.z, v1.w};
    #pragma unroll
    for (int j = 0; j < 8; ++j) h[(hf * 8 + j) * 137 + ch] = vv[j];
  }
  __syncthreads();
  pack_frags(h, XH, XL, MU, RS, nullptr, nullptr, false, tid);
  __syncthreads();

  const float* Bp[3] = {b0, b1, b2};
  const float* Gp[3] = {g0, g1, g2};
  const float* Ep[3] = {e0, e1, e2};

  for (int L = 0; L < 3; ++L) {
    const int ct0 = 2 * wv, ct1 = 2 * wv + 1;
    float bb0 = Bp[L][ct0 * 16 + l16], bb1 = Bp[L][ct1 * 16 + l16];
    f32x4_t ac0, ac1;
    ac0[0] = bb0; ac0[1] = bb0; ac0[2] = bb0; ac0[3] = bb0;
    ac1[0] = bb1; ac1[1] = bb1; ac1[2] = bb1; ac1[3] = bb1;
    const uint4* wf = (const uint4*)(ws + OFF_WF) + (size_t)L * 4096;
    #pragma unroll
    for (int kt = 0; kt < 8; ++kt) {
      H4 ah, al;
      ah.u = XH[kt * 64 + lane];
      al.u = XL[kt * 64 + lane];
      uint4 q0 = wf[(kt * 8 + ct0) * 64 + lane];
      uint4 q1 = wf[(kt * 8 + ct1) * 64 + lane];
      H4 bh0, bl0, bh1, bl1;
      bh0.u.x = q0.x; bh0.u.y = q0.y; bl0.u.x = q0.z; bl0.u.y = q0.w;
      bh1.u.x = q1.x; bh1.u.y = q1.y; bl1.u.x = q1.z; bl1.u.y = q1.w;
      ac0 = __builtin_amdgcn_mfma_f32_16x16x16f16(ah.h4, bl0.h4, ac0, 0, 0, 0);
      ac0 = __builtin_amdgcn_mfma_f32_16x16x16f16(al.h4, bh0.h4, ac0, 0, 0, 0);
      ac0 = __builtin_amdgcn_mfma_f32_16x16x16f16(ah.h4, bh0.h4, ac0, 0, 0, 0);
      ac1 = __builtin_amdgcn_mfma_f32_16x16x16f16(ah.h4, bl1.h4, ac1, 0, 0, 0);
      ac1 = __builtin_amdgcn_mfma_f32_16x16x16f16(al.h4, bh1.h4, ac1, 0, 0, 0);
      ac1 = __builtin_amdgcn_mfma_f32_16x16x16f16(ah.h4, bh1.h4, ac1, 0, 0, 0);
    }
    // D -> h: row(pos) = quad*4+r, col(ch) = ct*16+l16
    #pragma unroll
    for (int r = 0; r < 4; ++r) {
      h[(quad * 4 + r) * 137 + ct0 * 16 + l16] = ac0[r];
      h[(quad * 4 + r) * 137 + ct1 * 16 + l16] = ac1[r];
    }
    __syncthreads();
    // LN stats: 16 threads per pos
    {
      int p = tid >> 4, sb = tid & 15;
      float s = 0.f, q = 0.f;
      #pragma unroll
      for (int j = 0; j < 8; ++j) {
        float v = h[p * 137 + sb + 16 * j];
        s += v; q += v * v;
      }
      #pragma unroll
      for (int m2 = 1; m2 < 16; m2 <<= 1) {
        s += __shfl_xor(s, m2, 64);
        q += __shfl_xor(q, m2, 64);
      }
      if (sb == 0) {
        float mu = s * (1.0f / CEE);
        MU[p] = mu;
        RS[p] = rsqrtf(q * (1.0f / CEE) - mu * mu + 1e-5f);
      }
    }
    __syncthreads();
    pack_frags(h, XH, XL, MU, RS, Gp[L], Ep[L], true, tid);
    __syncthreads();
  }

  // final layer CE -> 256: wave handles ct = wv*4 .. wv*4+3
  {
    const uint4* wf = (const uint4*)(ws + OFF_W3F);
    f32x4_t ac[4];
    #pragma unroll
    for (int c = 0; c < 4; ++c) {
      float bb = b3[(wv * 4 + c) * 16 + l16];
      ac[c][0] = bb; ac[c][1] = bb; ac[c][2] = bb; ac[c][3] = bb;
    }
    #pragma unroll
    for (int kt = 0; kt < 8; ++kt) {
      H4 ah, al;
      ah.u = XH[kt * 64 + lane];
      al.u = XL[kt * 64 + lane];
      #pragma unroll
      for (int c = 0; c < 4; ++c) {
        uint4 q = wf[(kt * 16 + wv * 4 + c) * 64 + lane];
        H4 bh, bl;
        bh.u.x = q.x; bh.u.y = q.y; bl.u.x = q.z; bl.u.y = q.w;
        ac[c] = __builtin_amdgcn_mfma_f32_16x16x16f16(ah.h4, bl.h4, ac[c], 0, 0, 0);
        ac[c] = __builtin_amdgcn_mfma_f32_16x16x16f16(al.h4, bh.h4, ac[c], 0, 0, 0);
        ac[c] = __builtin_amdgcn_mfma_f32_16x16x16f16(ah.h4, bh.h4, ac[c], 0, 0, 0);
      }
    }
    #pragma unroll
    for (int c = 0; c < 4; ++c)
      #pragma unroll
      for (int r = 0; r < 4; ++r)
        h2[(quad * 4 + r) * 265 + (wv * 4 + c) * 16 + l16] = ac[c][r];
  }
  __syncthreads();

  // film write: thread = ch (256), 16 contiguous tc
  {
    int ch = tid;
    float vv[16];
    #pragma unroll
    for (int t = 0; t < 16; ++t) vv[t] = h2[t * 265 + ch];
    float* dst = ws + OFF_FILM + ((size_t)(b * 256 + ch)) * TCC + tc0;
    *(float4*)(dst) = make_float4(vv[0], vv[1], vv[2], vv[3]);
    *(float4*)(dst + 4) = make_float4(vv[4], vv[5], vv[6], vv[7]);
    *(float4*)(dst + 8) = make_float4(vv[8], vv[9], vv[10], vv[11]);
    *(float4*)(dst + 12) = make_float4(vv[12], vv[13], vv[14], vv[15]);
  }
  // S epilogue: S[b][tc] = sum_n mixw[n] * beta_n (ch 192..255)
  if (wv == 0) {
    float mw = mixw[lane];
    for (int t = 0; t < 16; ++t) {
      float v = h2[t * 265 + 192 + lane] * mw;
      #pragma unroll
      for (int m2 = 1; m2 < 64; m2 <<= 1) v += __shfl_xor(v, m2, 64);
      if (lane == 0) ws[OFF_SB + b * TCC + tc0 + t] = v;
    }
  }
}

// ---------------- kernel 2: FiLM + dual-MFMA waveshaper -> partials --------
// grid: 256 t-tiles x 4 batches x 4 channel-quarters; block 256 (4 waves)
__global__ __launch_bounds__(256, 8) void k_shape(
    const float* __restrict__ exciter,
    const float* __restrict__ ws,
    const float* __restrict__ mixw,
    float* __restrict__ part) {
  const int tid = threadIdx.x;
  const int lane = tid & 63;
  const int wv = tid >> 6;
  const int bx = blockIdx.x;
  const int blk = bx & 255;
  const int b = (bx >> 8) & 3;
  const int quarter = bx >> 10;
  const int n0 = quarter * 16;
  const int t0_blk = blk * 256;
  const int tcbase = blk * 4 - 1;

  __shared__ __align__(16) float FLp[16 * 48];    // [n][j 0..5][8]: gv,gd,bv,bd,nv,nd,-,-
  __shared__ float Spair[12];
  __shared__ __align__(16) float W0s[16 * 16], B0s[16 * 16], B1s[16 * 16];
  __shared__ float B2s[16];

  if (tid < 16 * 16) {
    W0s[tid] = ws[OFF_W0S + n0 * 16 + tid];
    B0s[tid] = ws[OFF_B0S + n0 * 16 + tid];
    B1s[tid] = ws[OFF_B1S + n0 * 16 + tid];
  }
  if (tid < 16) B2s[tid] = ws[OFF_B2S + n0 + tid];
  if (tid < 96) {
    int n = tid / 6, j = tid - n * 6;
    int tc = tcbase + j; tc = tc < 0 ? 0 : (tc > 1023 ? 1023 : tc);
    int tcn = tcbase + j + 1; tcn = tcn < 0 ? 0 : (tcn > 1023 ? 1023 : tcn);
    const float* fb = ws + OFF_FILM + ((size_t)(b * 256 + n0 + n)) * TCC;
    float g_v = fb[tc], g_n = fb[tcn];
    float b_v = fb[64 * TCC + tc], b_n = fb[64 * TCC + tcn];
    float n_v = fb[128 * TCC + tc], n_n = fb[128 * TCC + tcn];
    float mwn = mixw[n0 + n];
    float* d = FLp + n * 48 + j * 8;
    d[0] = g_v; d[1] = b_v;
    d[2] = g_n - g_v; d[3] = b_n - b_v;
    d[4] = n_v * mwn; d[5] = (n_n - n_v) * mwn;
  }
  if (tid >= 96 && tid < 102 && quarter == 0) {
    int j = tid - 96;
    int tc = tcbase + j; tc = tc < 0 ? 0 : (tc > 1023 ? 1023 : tc);
    int tcn = tcbase + j + 1; tcn = tcn < 0 ? 0 : (tcn > 1023 ? 1023 : tcn);
    float s0 = ws[OFF_SB + b * TCC + tc];
    float s1 = ws[OFF_SB + b * TCC + tcn];
    Spair[2 * j] = s0; Spair[2 * j + 1] = s1 - s0;
  }
  __syncthreads();

  const int t_own = t0_blk + wv * 64 + lane;
  float pos = ((float)t_own + 0.5f) * (1.0f / 64.0f) - 0.5f;
  pos = fminf(fmaxf(pos, 0.0f), 1023.0f);
  float fi = floorf(pos);
  int i0 = (int)fi;
  const float frac = pos - fi;
  const int j0 = i0 - tcbase;        // in [0,4]

  const int quad = lane >> 4;
  const int l16 = lane & 15;

  float acc = 0.0f;
  const float* excp = exciter + ((size_t)(b * NWS + n0)) * TT + t_own;
  const uint4* afp = (const uint4*)(ws + OFF_AFRAG) + (size_t)n0 * 64 + lane;

  f32x4_t czero; czero[0] = 0.f; czero[1] = 0.f; czero[2] = 0.f; czero[3] = 0.f;

  float ev = excp[0];
  uint4 af = afp[0];
  #pragma unroll 2
  for (int n = 0; n < 16; ++n) {
    // branch-free prefetch (index wraps on last iter; value unused)
    int nn = (n + 1) & 15;
    float ev_n = excp[(size_t)nn * TT];
    uint4 af_n = afp[nn * 64];

    const float* fp = FLp + n * 48 + j0 * 8;
    float4 gb = *(const float4*)(fp);        // gv, bv, gd, bd
    float2 np = *(const float2*)(fp + 4);
    f32x2_t vv; vv[0] = gb.x; vv[1] = gb.y;
    f32x2_t dd; dd[0] = gb.z; dd[1] = gb.w;
    f32x2_t fr2; fr2[0] = frac; fr2[1] = frac;
    f32x2_t gibi = dd * fr2 + vv;            // packed fma candidate
    float gnp = fmaf(np.y, frac, np.x);
    float x = fmaf(gibi[0], ev, gibi[1]);

    f32x4_t w0f = *(const f32x4_t*)(W0s + n * 16 + quad * 4);
    f32x4_t b0f = *(const f32x4_t*)(B0s + n * 16 + quad * 4);
    f32x4_t b1f = *(const f32x4_t*)(B1s + n * 16 + quad * 4);
    float b2v = B2s[n];
    H4 a1, a2;
    a1.u.x = af.x; a1.u.y = af.y;
    a2.u.x = af.z; a2.u.y = af.w;

    float yown = 0.0f;
    #pragma unroll
    for (int g = 0; g < 4; ++g) {
      float xg = __shfl(x, g * 16 + l16, 64);
      float s0 = sinrev(fmaf(xg, w0f[0], b0f[0]));
      float s1 = sinrev(fmaf(xg, w0f[1], b0f[1]));
      float s2 = sinrev(fmaf(xg, w0f[2], b0f[2]));
      float s3 = sinrev(fmaf(xg, w0f[3], b0f[3]));
      H4 bf1;
      bf1.f2[0] = __builtin_amdgcn_cvt_pkrtz(s0, s1);
      bf1.f2[1] = __builtin_amdgcn_cvt_pkrtz(s2, s3);
      f32x4_t d1 = __builtin_amdgcn_mfma_f32_16x16x16f16(a1.h4, bf1.h4, b1f, 0, 0, 0);
      float u0 = sinrev(d1[0]);
      float u1 = sinrev(d1[1]);
      float u2 = sinrev(d1[2]);
      float u3 = sinrev(d1[3]);
      H4 bf2;
      bf2.f2[0] = __builtin_amdgcn_cvt_pkrtz(u0, u1);
      bf2.f2[1] = __builtin_amdgcn_cvt_pkrtz(u2, u3);
      f32x4_t d2 = __builtin_amdgcn_mfma_f32_16x16x16f16(a2.h4, bf2.h4, czero, 0, 0, 0);
      yown = (quad == g) ? d2[0] : yown;   // all D2 rows equal; pick own group
    }
    float z = sinrev(yown + b2v);
    acc = fmaf(gnp, z, acc);
    ev = ev_n; af = af_n;
  }
  if (quarter == 0) {
    float2 sp = *(const float2*)(Spair + 2 * j0);
    acc += fmaf(sp.y, frac, sp.x);
  }
  part[((size_t)(quarter * NB + b)) * TT + t_own] = acc;
}

// ---------------- kernel 3: combine partials, x4 repeat, mixer bias --------
__global__ __launch_bounds__(256) void k_mix(
    const float* __restrict__ part,
    const float* __restrict__ mixb,
    float* __restrict__ out) {
  int idx = blockIdx.x * 256 + threadIdx.x;   // over B*T/4
  float m = mixb[0];
  float4 a = ((const float4*)part)[idx];
  float4 c = ((const float4*)(part + (size_t)NB * TT))[idx];
  float4 d = ((const float4*)(part + (size_t)2 * NB * TT))[idx];
  float4 e = ((const float4*)(part + (size_t)3 * NB * TT))[idx];
  float4* o = (float4*)(out + (size_t)idx * 16);
  float s0 = a.x + c.x + d.x + e.x + m;
  float s1 = a.y + c.y + d.y + e.y + m;
  float s2 = a.z + c.z + d.z + e.z + m;
  float s3 = a.w + c.w + d.w + e.w + m;
  o[0] = make_float4(s0, s0, s0, s0);
  o[1] = make_float4(s1, s1, s1, s1);
  o[2] = make_float4(s2, s2, s2, s2);
  o[3] = make_float4(s3, s3, s3, s3);
}

extern "C" void kernel_launch(void* const* d_in, const int* in_sizes, int n_in,
                              void* d_out, int out_size, void* d_ws, size_t ws_size,
                              hipStream_t stream) {
  const float* exciter = (const float*)d_in[0];
  const float* ce      = (const float*)d_in[1];
  const float* w0  = (const float*)d_in[2];
  const float* b0  = (const float*)d_in[3];
  const float* g0  = (const float*)d_in[4];
  const float* e0  = (const float*)d_in[5];
  const float* w1  = (const float*)d_in[6];
  const float* b1  = (const float*)d_in[7];
  const float* g1  = (const float*)d_in[8];
  const float* e1  = (const float*)d_in[9];
  const float* w2  = (const float*)d_in[10];
  const float* b2  = (const float*)d_in[11];
  const float* g2  = (const float*)d_in[12];
  const float* e2  = (const float*)d_in[13];
  const float* w3  = (const float*)d_in[14];
  const float* b3  = (const float*)d_in[15];
  const float* iscale = (const float*)d_in[16];
  const float* sw0 = (const float*)d_in[17];
  const float* sb0 = (const float*)d_in[18];
  const float* sw1 = (const float*)d_in[19];
  const float* sb1 = (const float*)d_in[20];
  const float* sw2 = (const float*)d_in[21];
  const float* sb2 = (const float*)d_in[22];
  const float* mixw = (const float*)d_in[23];
  const float* mixb = (const float*)d_in[24];

  float* ws = (float*)d_ws;

  hipLaunchKernelGGL(k_prep, dim3(96), dim3(256), 0, stream,
                     iscale, sw0, sb0, sw1, sb1, sw2, sb2, w0, w1, w2, w3, ws);
  hipLaunchKernelGGL(k_mlp, dim3(256), dim3(256), 0, stream,
                     ce, b0, g0, e0, b1, g1, e1, b2, g2, e2, b3, mixw, ws);
  hipLaunchKernelGGL(k_shape, dim3(4096), dim3(256), 0, stream,
                     exciter, ws, mixw, ws + OFF_PART);
  hipLaunchKernelGGL(k_mix, dim3(256), dim3(256), 0, stream,
                     ws + OFF_PART, mixb, (float*)d_out);
}

// Round 11
// 210.598 us; speedup vs baseline: 1.0401x; 1.0401x over previous
//
#include <hip/hip_runtime.h>
#include <stdint.h>

#define NB 4
#define NWS 64
#define TT 65536
#define TCC 1024
#define CEE 128
#define WW 16

#define INV2PI 0.15915494309189535f

// ws layout (float offsets)
#define OFF_FILM  0                           // 1048576
#define OFF_SB    (OFF_FILM + NB*256*TCC)     // 4096: S[b][tc] = sum_n mw*bn
#define OFF_W0S   (OFF_SB + NB*TCC)           // 1024
#define OFF_B0S   (OFF_W0S + 1024)
#define OFF_B1S   (OFF_B0S + 1024)
#define OFF_B2S   (OFF_B1S + 1024)            // 64
#define OFF_AFRAG (OFF_B2S + 64)              // 4096 uint4 = 16384 floats
#define OFF_WF    (OFF_AFRAG + 16384)         // 12288 uint4 = 49152 floats (hidden W frags)
#define OFF_W3F   (OFF_WF + 49152)            // 8192 uint4 = 32768 floats (final W frags)
#define OFF_PART  (OFF_W3F + 32768)           // 4*NB*TT floats

typedef _Float16 half4_t __attribute__((ext_vector_type(4)));
typedef _Float16 half2_t __attribute__((ext_vector_type(2)));
typedef __fp16 fp16x2_t __attribute__((ext_vector_type(2)));
typedef float f32x4_t __attribute__((ext_vector_type(4)));

union H4 { half4_t h4; half2_t h2[2]; fp16x2_t f2[2]; uint2 u; };

__device__ __forceinline__ float sinrev(float r) {
  // sin(2*pi*r); args bounded well inside HW +-256 revolution range
  return __builtin_amdgcn_sinf(r);
}

// ---------------- prep: shaper weights + MLP weight fragments --------------
__global__ __launch_bounds__(256) void k_prep(
    const float* __restrict__ iscale,
    const float* __restrict__ sw0, const float* __restrict__ sb0,
    const float* __restrict__ sw1, const float* __restrict__ sb1,
    const float* __restrict__ sw2, const float* __restrict__ sb2,
    const float* __restrict__ m0, const float* __restrict__ m1,
    const float* __restrict__ m2, const float* __restrict__ m3,
    float* __restrict__ ws) {
  const int tid = threadIdx.x;
  const int bx = blockIdx.x;
  if (bx < 16) {
    int i = bx * 256 + tid;             // 0..4095
    if (i < NWS * WW) {
      int n = i / WW;
      ws[OFF_W0S + i] = sw0[i] * iscale[n] * INV2PI;
      ws[OFF_B0S + i] = sb0[i] * INV2PI;
      ws[OFF_B1S + i] = sb1[i] * INV2PI;
    }
    if (i < NWS) ws[OFF_B2S + i] = sb2[i] * INV2PI;
    {
      int n = i >> 6, l = i & 63;
      int m = l & 15, k0 = (l >> 4) * 4;
      H4 a1, a2;
      #pragma unroll
      for (int j = 0; j < 4; ++j) {
        a1.h4[j] = (_Float16)(sw1[(n * 16 + m) * 16 + k0 + j] * INV2PI);
        a2.h4[j] = (_Float16)(sw2[n * 16 + k0 + j] * INV2PI);
      }
      uint4 o; o.x = a1.u.x; o.y = a1.u.y; o.z = a2.u.x; o.w = a2.u.y;
      ((uint4*)(ws + OFF_AFRAG))[i] = o;
    }
  } else if (bx < 64) {
    // hidden-layer W fragments: B[k][n=ch]: lane holds W[ct*16+l16][kt*16+quad*4+j]
    int i = (bx - 16) * 256 + tid;      // 0..12287 = ((L*8+kt)*8+ct)*64+lane
    int l = i & 63, ct = (i >> 6) & 7, kt = (i >> 9) & 7, L = i >> 12;
    const float* W = (L == 0) ? m0 : (L == 1 ? m1 : m2);
    int o = ct * 16 + (l & 15);
    int k0 = kt * 16 + (l >> 4) * 4;
    H4 hi, lo;
    #pragma unroll
    for (int j = 0; j < 4; ++j) {
      float v = W[o * CEE + k0 + j];
      _Float16 h = (_Float16)v;
      hi.h4[j] = h;
      lo.h4[j] = (_Float16)(v - (float)h);
    }
    uint4 q; q.x = hi.u.x; q.y = hi.u.y; q.z = lo.u.x; q.w = lo.u.y;
    ((uint4*)(ws + OFF_WF))[i] = q;
  } else {
    // final-layer (CE->256) fragments: (kt*16 + ct)*64 + lane
    int i = (bx - 64) * 256 + tid;      // 0..8191
    int l = i & 63, ct = (i >> 6) & 15, kt = i >> 10;
    int o = ct * 16 + (l & 15);
    int k0 = kt * 16 + (l >> 4) * 4;
    H4 hi, lo;
    #pragma unroll
    for (int j = 0; j < 4; ++j) {
      float v = m3[o * CEE + k0 + j];
      _Float16 h = (_Float16)v;
      hi.h4[j] = h;
      lo.h4[j] = (_Float16)(v - (float)h);
    }
    uint4 q; q.x = hi.u.x; q.y = hi.u.y; q.z = lo.u.x; q.w = lo.u.y;
    ((uint4*)(ws + OFF_W3F))[i] = q;
  }
}

// pack x (16 pos x 128 ch fp32 in h) into MFMA A-fragments, f16 hi/lo split
__device__ __forceinline__ void pack_frags(
    const float* h, uint2* XH, uint2* XL,
    const float* MU, const float* RS,
    const float* __restrict__ g, const float* __restrict__ e,
    bool doLN, int tid) {
  #pragma unroll
  for (int i = 0; i < 2; ++i) {
    int w = tid + i * 256;
    int l = w & 63, kt = w >> 6;
    int m = l & 15, k0 = kt * 16 + (l >> 4) * 4;
    float x[4];
    #pragma unroll
    for (int j = 0; j < 4; ++j) {
      float v = h[m * 137 + k0 + j];
      if (doLN) {
        v = (v - MU[m]) * RS[m] * g[k0 + j] + e[k0 + j];
        v = fmaxf(v, 0.01f * v);
      }
      x[j] = v;
    }
    H4 hi;
    hi.f2[0] = __builtin_amdgcn_cvt_pkrtz(x[0], x[1]);
    hi.f2[1] = __builtin_amdgcn_cvt_pkrtz(x[2], x[3]);
    float l0 = x[0] - (float)hi.h4[0];
    float l1 = x[1] - (float)hi.h4[1];
    float l2 = x[2] - (float)hi.h4[2];
    float l3 = x[3] - (float)hi.h4[3];
    H4 lo;
    lo.f2[0] = __builtin_amdgcn_cvt_pkrtz(l0, l1);
    lo.f2[1] = __builtin_amdgcn_cvt_pkrtz(l2, l3);
    XH[kt * 64 + l] = hi.u;
    XL[kt * 64 + l] = lo.u;
  }
}

// ---------------- kernel 1: MFMA TimeDistributedMLP -> film + S ------------
// grid: 4 b x 64 tc-tiles = 256 blocks; block 256 threads (4 waves)
__global__ __launch_bounds__(256) void k_mlp(
    const float* __restrict__ ce,
    const float* __restrict__ b0, const float* __restrict__ g0, const float* __restrict__ e0,
    const float* __restrict__ b1, const float* __restrict__ g1, const float* __restrict__ e1,
    const float* __restrict__ b2, const float* __restrict__ g2, const float* __restrict__ e2,
    const float* __restrict__ b3,
    const float* __restrict__ mixw,
    float* __restrict__ ws) {
  const int tid = threadIdx.x;
  const int lane = tid & 63;
  const int wv = tid >> 6;
  const int l16 = lane & 15;
  const int quad = lane >> 4;
  const int bx = blockIdx.x;
  const int b = bx >> 6;
  const int tc0 = (bx & 63) * 16;

  __shared__ float h[16 * 137];        // [pos][ch] fp32
  __shared__ float h2[16 * 265];       // final [pos][ch256]
  __shared__ uint2 XH[8 * 64], XL[8 * 64];
  __shared__ float MU[16], RS[16];

  // stage ce tile -> h (transpose)
  {
    int ch = tid >> 1, hf = tid & 1;
    const float* src = ce + ((size_t)(b * CEE + ch)) * TCC + tc0 + hf * 8;
    float4 v0 = *(const float4*)src;
    float4 v1 = *(const float4*)(src + 4);
    float vv[8] = {v0.x, v0.y, v0.z, v0.w, v1.x, v1.y, v1.z, v1.w};
    #pragma unroll
    for (int j = 0; j < 8; ++j) h[(hf * 8 + j) * 137 + ch] = vv[j];
  }
  __syncthreads();
  pack_frags(h, XH, XL, MU, RS, nullptr, nullptr, false, tid);
  __syncthreads();

  const float* Bp[3] = {b0, b1, b2};
  const float* Gp[3] = {g0, g1, g2};
  const float* Ep[3] = {e0, e1, e2};

  for (int L = 0; L < 3; ++L) {
    const int ct0 = 2 * wv, ct1 = 2 * wv + 1;
    float bb0 = Bp[L][ct0 * 16 + l16], bb1 = Bp[L][ct1 * 16 + l16];
    f32x4_t ac0, ac1;
    ac0[0] = bb0; ac0[1] = bb0; ac0[2] = bb0; ac0[3] = bb0;
    ac1[0] = bb1; ac1[1] = bb1; ac1[2] = bb1; ac1[3] = bb1;
    const uint4* wf = (const uint4*)(ws + OFF_WF) + (size_t)L * 4096;
    #pragma unroll
    for (int kt = 0; kt < 8; ++kt) {
      H4 ah, al;
      ah.u = XH[kt * 64 + lane];
      al.u = XL[kt * 64 + lane];
      uint4 q0 = wf[(kt * 8 + ct0) * 64 + lane];
      uint4 q1 = wf[(kt * 8 + ct1) * 64 + lane];
      H4 bh0, bl0, bh1, bl1;
      bh0.u.x = q0.x; bh0.u.y = q0.y; bl0.u.x = q0.z; bl0.u.y = q0.w;
      bh1.u.x = q1.x; bh1.u.y = q1.y; bl1.u.x = q1.z; bl1.u.y = q1.w;
      ac0 = __builtin_amdgcn_mfma_f32_16x16x16f16(ah.h4, bl0.h4, ac0, 0, 0, 0);
      ac0 = __builtin_amdgcn_mfma_f32_16x16x16f16(al.h4, bh0.h4, ac0, 0, 0, 0);
      ac0 = __builtin_amdgcn_mfma_f32_16x16x16f16(ah.h4, bh0.h4, ac0, 0, 0, 0);
      ac1 = __builtin_amdgcn_mfma_f32_16x16x16f16(ah.h4, bl1.h4, ac1, 0, 0, 0);
      ac1 = __builtin_amdgcn_mfma_f32_16x16x16f16(al.h4, bh1.h4, ac1, 0, 0, 0);
      ac1 = __builtin_amdgcn_mfma_f32_16x16x16f16(ah.h4, bh1.h4, ac1, 0, 0, 0);
    }
    // D -> h: row(pos) = quad*4+r, col(ch) = ct*16+l16
    #pragma unroll
    for (int r = 0; r < 4; ++r) {
      h[(quad * 4 + r) * 137 + ct0 * 16 + l16] = ac0[r];
      h[(quad * 4 + r) * 137 + ct1 * 16 + l16] = ac1[r];
    }
    __syncthreads();
    // LN stats: 16 threads per pos
    {
      int p = tid >> 4, sb = tid & 15;
      float s = 0.f, q = 0.f;
      #pragma unroll
      for (int j = 0; j < 8; ++j) {
        float v = h[p * 137 + sb + 16 * j];
        s += v; q += v * v;
      }
      #pragma unroll
      for (int m2 = 1; m2 < 16; m2 <<= 1) {
        s += __shfl_xor(s, m2, 64);
        q += __shfl_xor(q, m2, 64);
      }
      if (sb == 0) {
        float mu = s * (1.0f / CEE);
        MU[p] = mu;
        RS[p] = rsqrtf(q * (1.0f / CEE) - mu * mu + 1e-5f);
      }
    }
    __syncthreads();
    pack_frags(h, XH, XL, MU, RS, Gp[L], Ep[L], true, tid);
    __syncthreads();
  }

  // final layer CE -> 256: wave handles ct = wv*4 .. wv*4+3
  {
    const uint4* wf = (const uint4*)(ws + OFF_W3F);
    f32x4_t ac[4];
    #pragma unroll
    for (int c = 0; c < 4; ++c) {
      float bb = b3[(wv * 4 + c) * 16 + l16];
      ac[c][0] = bb; ac[c][1] = bb; ac[c][2] = bb; ac[c][3] = bb;
    }
    #pragma unroll
    for (int kt = 0; kt < 8; ++kt) {
      H4 ah, al;
      ah.u = XH[kt * 64 + lane];
      al.u = XL[kt * 64 + lane];
      #pragma unroll
      for (int c = 0; c < 4; ++c) {
        uint4 q = wf[(kt * 16 + wv * 4 + c) * 64 + lane];
        H4 bh, bl;
        bh.u.x = q.x; bh.u.y = q.y; bl.u.x = q.z; bl.u.y = q.w;
        ac[c] = __builtin_amdgcn_mfma_f32_16x16x16f16(ah.h4, bl.h4, ac[c], 0, 0, 0);
        ac[c] = __builtin_amdgcn_mfma_f32_16x16x16f16(al.h4, bh.h4, ac[c], 0, 0, 0);
        ac[c] = __builtin_amdgcn_mfma_f32_16x16x16f16(ah.h4, bh.h4, ac[c], 0, 0, 0);
      }
    }
    #pragma unroll
    for (int c = 0; c < 4; ++c)
      #pragma unroll
      for (int r = 0; r < 4; ++r)
        h2[(quad * 4 + r) * 265 + (wv * 4 + c) * 16 + l16] = ac[c][r];
  }
  __syncthreads();

  // film write: thread = ch (256), 16 contiguous tc
  {
    int ch = tid;
    float vv[16];
    #pragma unroll
    for (int t = 0; t < 16; ++t) vv[t] = h2[t * 265 + ch];
    float* dst = ws + OFF_FILM + ((size_t)(b * 256 + ch)) * TCC + tc0;
    *(float4*)(dst) = make_float4(vv[0], vv[1], vv[2], vv[3]);
    *(float4*)(dst + 4) = make_float4(vv[4], vv[5], vv[6], vv[7]);
    *(float4*)(dst + 8) = make_float4(vv[8], vv[9], vv[10], vv[11]);
    *(float4*)(dst + 12) = make_float4(vv[12], vv[13], vv[14], vv[15]);
  }
  // S epilogue: S[b][tc] = sum_n mixw[n] * beta_n (ch 192..255)
  if (wv == 0) {
    float mw = mixw[lane];
    for (int t = 0; t < 16; ++t) {
      float v = h2[t * 265 + 192 + lane] * mw;
      #pragma unroll
      for (int m2 = 1; m2 < 64; m2 <<= 1) v += __shfl_xor(v, m2, 64);
      if (lane == 0) ws[OFF_SB + b * TCC + tc0 + t] = v;
    }
  }
}

// ---------------- kernel 2: FiLM + dual-MFMA waveshaper -> partials --------
// grid: 256 t-tiles x 4 batches x 4 channel-quarters; block 256 (4 waves)
__global__ __launch_bounds__(256, 8) void k_shape(
    const float* __restrict__ exciter,
    const float* __restrict__ ws,
    const float* __restrict__ mixw,
    float* __restrict__ part) {
  const int tid = threadIdx.x;
  const int lane = tid & 63;
  const int wv = tid >> 6;
  const int bx = blockIdx.x;
  const int blk = bx & 255;
  const int b = (bx >> 8) & 3;
  const int quarter = bx >> 10;
  const int n0 = quarter * 16;
  const int t0_blk = blk * 256;
  const int tcbase = blk * 4 - 1;

  __shared__ __align__(16) float FLp[16 * 48];    // [n][j 0..5][8]: gv,gd,bv,bd,nv,nd,-,-
  __shared__ float Spair[12];
  __shared__ __align__(16) float W0s[16 * 16], B0s[16 * 16], B1s[16 * 16];
  __shared__ float B2s[16];

  if (tid < 16 * 16) {
    W0s[tid] = ws[OFF_W0S + n0 * 16 + tid];
    B0s[tid] = ws[OFF_B0S + n0 * 16 + tid];
    B1s[tid] = ws[OFF_B1S + n0 * 16 + tid];
  }
  if (tid < 16) B2s[tid] = ws[OFF_B2S + n0 + tid];
  if (tid < 96) {
    int n = tid / 6, j = tid - n * 6;
    int tc = tcbase + j; tc = tc < 0 ? 0 : (tc > 1023 ? 1023 : tc);
    int tcn = tcbase + j + 1; tcn = tcn < 0 ? 0 : (tcn > 1023 ? 1023 : tcn);
    const float* fb = ws + OFF_FILM + ((size_t)(b * 256 + n0 + n)) * TCC;
    float g_v = fb[tc], g_n = fb[tcn];
    float b_v = fb[64 * TCC + tc], b_n = fb[64 * TCC + tcn];
    float n_v = fb[128 * TCC + tc], n_n = fb[128 * TCC + tcn];
    float mwn = mixw[n0 + n];
    float* d = FLp + n * 48 + j * 8;
    d[0] = g_v; d[1] = g_n - g_v;
    d[2] = b_v; d[3] = b_n - b_v;
    d[4] = n_v * mwn; d[5] = (n_n - n_v) * mwn;
  }
  if (tid >= 96 && tid < 102 && quarter == 0) {
    int j = tid - 96;
    int tc = tcbase + j; tc = tc < 0 ? 0 : (tc > 1023 ? 1023 : tc);
    int tcn = tcbase + j + 1; tcn = tcn < 0 ? 0 : (tcn > 1023 ? 1023 : tcn);
    float s0 = ws[OFF_SB + b * TCC + tc];
    float s1 = ws[OFF_SB + b * TCC + tcn];
    Spair[2 * j] = s0; Spair[2 * j + 1] = s1 - s0;
  }
  __syncthreads();

  const int t_own = t0_blk + wv * 64 + lane;
  float pos = ((float)t_own + 0.5f) * (1.0f / 64.0f) - 0.5f;
  pos = fminf(fmaxf(pos, 0.0f), 1023.0f);
  float fi = floorf(pos);
  int i0 = (int)fi;
  const float frac = pos - fi;
  const int j0 = i0 - tcbase;        // in [0,4]

  const int quad = lane >> 4;
  const int l16 = lane & 15;

  float acc = 0.0f;
  const float* excp = exciter + ((size_t)(b * NWS + n0)) * TT + t_own;
  const uint4* afp = (const uint4*)(ws + OFF_AFRAG) + (size_t)n0 * 64 + lane;

  float ev = excp[0];
  uint4 af = afp[0];
  for (int n = 0; n < 16; ++n) {
    float ev_n = 0.f; uint4 af_n = af;
    if (n < 15) {
      ev_n = excp[(size_t)(n + 1) * TT];
      af_n = afp[(n + 1) * 64];
    }
    const float* fp = FLp + n * 48 + j0 * 8;
    float4 gb = *(const float4*)(fp);
    float2 np = *(const float2*)(fp + 4);
    float gi = fmaf(gb.y, frac, gb.x);
    float bi = fmaf(gb.w, frac, gb.z);
    float gnp = fmaf(np.y, frac, np.x);
    float x = fmaf(gi, ev, bi);

    f32x4_t w0f = *(const f32x4_t*)(W0s + n * 16 + quad * 4);
    f32x4_t b0f = *(const f32x4_t*)(B0s + n * 16 + quad * 4);
    f32x4_t b1f = *(const f32x4_t*)(B1s + n * 16 + quad * 4);
    float b2v = B2s[n];
    f32x4_t c2; c2[0] = b2v; c2[1] = b2v; c2[2] = b2v; c2[3] = b2v;
    H4 a1, a2;
    a1.u.x = af.x; a1.u.y = af.y;
    a2.u.x = af.z; a2.u.y = af.w;

    float yown = 0.0f;
    #pragma unroll
    for (int g = 0; g < 4; ++g) {
      float xg = __shfl(x, g * 16 + l16, 64);
      float s0 = sinrev(fmaf(xg, w0f[0], b0f[0]));
      float s1 = sinrev(fmaf(xg, w0f[1], b0f[1]));
      float s2 = sinrev(fmaf(xg, w0f[2], b0f[2]));
      float s3 = sinrev(fmaf(xg, w0f[3], b0f[3]));
      H4 bf1;
      bf1.f2[0] = __builtin_amdgcn_cvt_pkrtz(s0, s1);
      bf1.f2[1] = __builtin_amdgcn_cvt_pkrtz(s2, s3);
      f32x4_t d1 = __builtin_amdgcn_mfma_f32_16x16x16f16(a1.h4, bf1.h4, b1f, 0, 0, 0);
      float u0 = sinrev(d1[0]);
      float u1 = sinrev(d1[1]);
      float u2 = sinrev(d1[2]);
      float u3 = sinrev(d1[3]);
      H4 bf2;
      bf2.f2[0] = __builtin_amdgcn_cvt_pkrtz(u0, u1);
      bf2.f2[1] = __builtin_amdgcn_cvt_pkrtz(u2, u3);
      f32x4_t d2 = __builtin_amdgcn_mfma_f32_16x16x16f16(a2.h4, bf2.h4, c2, 0, 0, 0);
      yown = (quad == g) ? d2[0] : yown;   // all D2 rows equal; pick own group
    }
    float z = sinrev(yown);                 // b2 already in C2
    acc = fmaf(gnp, z, acc);
    ev = ev_n; af = af_n;
  }
  if (quarter == 0) {
    float2 sp = *(const float2*)(Spair + 2 * j0);
    acc += fmaf(sp.y, frac, sp.x);
  }
  part[((size_t)(quarter * NB + b)) * TT + t_own] = acc;
}

// ---------------- kernel 3: combine partials, x4 repeat, mixer bias --------
__global__ __launch_bounds__(256) void k_mix(
    const float* __restrict__ part,
    const float* __restrict__ mixb,
    float* __restrict__ out) {
  int idx = blockIdx.x * 256 + threadIdx.x;   // over B*T/4
  float m = mixb[0];
  float4 a = ((const float4*)part)[idx];
  float4 c = ((const float4*)(part + (size_t)NB * TT))[idx];
  float4 d = ((const float4*)(part + (size_t)2 * NB * TT))[idx];
  float4 e = ((const float4*)(part + (size_t)3 * NB * TT))[idx];
  float4* o = (float4*)(out + (size_t)idx * 16);
  float s0 = a.x + c.x + d.x + e.x + m;
  float s1 = a.y + c.y + d.y + e.y + m;
  float s2 = a.z + c.z + d.z + e.z + m;
  float s3 = a.w + c.w + d.w + e.w + m;
  o[0] = make_float4(s0, s0, s0, s0);
  o[1] = make_float4(s1, s1, s1, s1);
  o[2] = make_float4(s2, s2, s2, s2);
  o[3] = make_float4(s3, s3, s3, s3);
}

extern "C" void kernel_launch(void* const* d_in, const int* in_sizes, int n_in,
                              void* d_out, int out_size, void* d_ws, size_t ws_size,
                              hipStream_t stream) {
  const float* exciter = (const float*)d_in[0];
  const float* ce      = (const float*)d_in[1];
  const float* w0  = (const float*)d_in[2];
  const float* b0  = (const float*)d_in[3];
  const float* g0  = (const float*)d_in[4];
  const float* e0  = (const float*)d_in[5];
  const float* w1  = (const float*)d_in[6];
  const float* b1  = (const float*)d_in[7];
  const float* g1  = (const float*)d_in[8];
  const float* e1  = (const float*)d_in[9];
  const float* w2  = (const float*)d_in[10];
  const float* b2  = (const float*)d_in[11];
  const float* g2  = (const float*)d_in[12];
  const float* e2  = (const float*)d_in[13];
  const float* w3  = (const float*)d_in[14];
  const float* b3  = (const float*)d_in[15];
  const float* iscale = (const float*)d_in[16];
  const float* sw0 = (const float*)d_in[17];
  const float* sb0 = (const float*)d_in[18];
  const float* sw1 = (const float*)d_in[19];
  const float* sb1 = (const float*)d_in[20];
  const float* sw2 = (const float*)d_in[21];
  const float* sb2 = (const float*)d_in[22];
  const float* mixw = (const float*)d_in[23];
  const float* mixb = (const float*)d_in[24];

  float* ws = (float*)d_ws;

  hipLaunchKernelGGL(k_prep, dim3(96), dim3(256), 0, stream,
                     iscale, sw0, sb0, sw1, sb1, sw2, sb2, w0, w1, w2, w3, ws);
  hipLaunchKernelGGL(k_mlp, dim3(256), dim3(256), 0, stream,
                     ce, b0, g0, e0, b1, g1, e1, b2, g2, e2, b3, mixw, ws);
  hipLaunchKernelGGL(k_shape, dim3(4096), dim3(256), 0, stream,
                     exciter, ws, mixw, ws + OFF_PART);
  hipLaunchKernelGGL(k_mix, dim3(256), dim3(256), 0, stream,
                     ws + OFF_PART, mixb, (float*)d_out);
}